// Round 6
// baseline (353.257 us; speedup 1.0000x reference)
//
#include <hip/hip_runtime.h>
#include <hip/hip_fp16.h>
#include <math.h>

#define N_NODES 50000
#define N_EDGES 800000
#define IN_C 96
#define HID_C 64
#define OUT_C 40
#define ALPHA 0.2f
#define NEG_SLOPE 0.01f
#define QCAP 131072  // per-partition queue capacity; mean 100k, ~100 sigma margin
#define NBLK 196     // cdiv(N_NODES, 256)

typedef _Float16 f16x8 __attribute__((ext_vector_type(8)));
typedef float f32x4 __attribute__((ext_vector_type(4)));
typedef int i32x4 __attribute__((ext_vector_type(4)));
typedef int i32x2 __attribute__((ext_vector_type(2)));

// streaming (zero-reuse) edge reads: non-temporal, don't pollute L1/L2
__device__ __forceinline__ int edge_at(const void* ei, int is64, long long pos) {
    return is64 ? (int)__builtin_nontemporal_load((const long long*)ei + pos)
                : __builtin_nontemporal_load((const int*)ei + pos);
}

// ---- zero deg + qtail + done-counter + zero-row init + edge dtype detect ----
// Row N_NODES of each feature buffer is the shared ZERO ROW targeted by the
// alignment-pad entries in csrc; it is never written by any other kernel.
__global__ void zero_detect_k(int* deg, int n, int* qtail, const unsigned int* ei, int* flag,
                              __half* bufA, __half* bufB, __half* bufC) {
    int i = blockIdx.x * blockDim.x + threadIdx.x;
    if (i < n) deg[i] = 0;
    if (i < 8) qtail[i] = 0;
    if (i == 1) flag[1] = 0;  // scan_p12 last-block ticket
    if (i >= 8 && i < 32) {   // 24 threads: 3 bufs x 8 float4 = zero row N
        int j = i - 8;
        __half* b = (j < 8) ? bufA : (j < 16) ? bufB : bufC;
        ((float4*)b)[(size_t)N_NODES * 8 + (j & 7)] = make_float4(0.f, 0.f, 0.f, 0.f);
    }
    if (i == 0) {
        int is64 = 1;
        for (int j = 1; j < 16; j += 2)
            if (ei[j] != 0u) is64 = 0;
        *flag = is64;
    }
}

// ---- phase A: one pass over edges; block-level partition reservation ----
__global__ void bucketA_k(const void* ei, const int* flag, int* __restrict__ deg,
                          int* __restrict__ qtail, int2* __restrict__ queue, int E) {
    __shared__ int cnt[8], qb[8];
    int f = *flag;
    int e0 = blockIdx.x * 1024;
    if (threadIdx.x < 8) cnt[threadIdx.x] = 0;
    __syncthreads();
    int s[4], d[4], p[4], r[4];
    #pragma unroll
    for (int k = 0; k < 4; ++k) {
        int e = e0 + threadIdx.x + k * 256;
        if (e < E) {
            d[k] = edge_at(ei, f, (long long)E + e);
            s[k] = edge_at(ei, f, e);
            atomicAdd(&deg[d[k]], 1);
            p[k] = d[k] / (N_NODES / 8);
            if (p[k] > 7) p[k] = 7;
            r[k] = atomicAdd(&cnt[p[k]], 1);
        } else p[k] = -1;
    }
    __syncthreads();
    if (threadIdx.x < 8) qb[threadIdx.x] = atomicAdd(&qtail[threadIdx.x], cnt[threadIdx.x]);
    __syncthreads();
    #pragma unroll
    for (int k = 0; k < 4; ++k) {
        if (p[k] >= 0) {
            int pos = qb[p[k]] + r[k];
            if (pos < QCAP) queue[(size_t)p[k] * QCAP + pos] = make_int2(s[k], d[k]);
        }
    }
}

// ---- fused scan p1+p2 over PADDED deg ((d+3)&~3): per-block sums, then the
// LAST block to finish (atomic ticket) exclusive-scans the block sums.
__global__ void scan_p12_k(const int* __restrict__ deg, int* __restrict__ part,
                           int* __restrict__ rowptr, int* __restrict__ done, int n) {
    __shared__ int sm[256];
    __shared__ int lastFlag;
    int t = threadIdx.x, i = blockIdx.x * 256 + t;
    int v = (i < n) ? ((deg[i] + 3) & ~3) : 0;
    sm[t] = v;
    __syncthreads();
    for (int off = 1; off < 256; off <<= 1) {
        int u = (t >= off) ? sm[t - off] : 0;
        __syncthreads();
        sm[t] += u;
        __syncthreads();
    }
    if (t == 255) part[blockIdx.x] = sm[255];
    __threadfence();
    if (t == 0) lastFlag = (atomicAdd(done, 1) == (int)gridDim.x - 1);
    __syncthreads();
    if (!lastFlag) return;
    // last block: all part[] writes are fence-ordered before our ticket won
    int pv = (t < NBLK) ? part[t] : 0;
    sm[t] = pv;
    __syncthreads();
    for (int off = 1; off < 256; off <<= 1) {
        int u = (t >= off) ? sm[t - off] : 0;
        __syncthreads();
        sm[t] += u;
        __syncthreads();
    }
    if (t < NBLK) part[t] = sm[t] - pv;  // exclusive
    if (t == 255) rowptr[n] = sm[255];
}

// scan_p3 + bucket histogram + pad-slot fill (pads -> zero-row index N)
__global__ void scan_p3_k(const int* __restrict__ deg, const int* __restrict__ part,
                          int* __restrict__ rowptr, int* __restrict__ cursor,
                          float* __restrict__ dinv, int* __restrict__ bcnt,
                          int* __restrict__ csrc, int n) {
    __shared__ int sm[256];
    __shared__ int h[64];
    int t = threadIdx.x, i = blockIdx.x * 256 + t;
    if (t < 64) h[t] = 0;
    int d = (i < n) ? deg[i] : 0;
    int v = (d + 3) & ~3;
    sm[t] = v;
    __syncthreads();
    for (int off = 1; off < 256; off <<= 1) {
        int u = (t >= off) ? sm[t - off] : 0;
        __syncthreads();
        sm[t] += u;
        __syncthreads();
    }
    if (i < n) {
        int excl = sm[t] - v + part[blockIdx.x];
        rowptr[i] = excl;
        cursor[i] = excl;
        dinv[i] = rsqrtf((float)d + 1.0f);  // +1 self loop
        for (int k = d; k < v; ++k) csrc[excl + k] = N_NODES;  // pad -> zero row
        int dd = d; if (dd > 63) dd = 63;
        atomicAdd(&h[63 - dd], 1);          // bucket = 63-deg (descending)
    }
    __syncthreads();
    if (t < 64) bcnt[blockIdx.x * 64 + t] = h[t];
}

__global__ void bscanA_k(const int* __restrict__ bcnt, int* __restrict__ bbase,
                         int* __restrict__ tot, int nb) {
    __shared__ int sm[256];
    int b = blockIdx.x;
    int t = threadIdx.x;
    int v = (t < nb) ? bcnt[t * 64 + b] : 0;
    sm[t] = v;
    __syncthreads();
    for (int off = 1; off < 256; off <<= 1) {
        int u = (t >= off) ? sm[t - off] : 0;
        __syncthreads();
        sm[t] += u;
        __syncthreads();
    }
    if (t < nb) bbase[t * 64 + b] = sm[t] - v;
    if (t == 255) tot[b] = sm[255];
}

// ---- fused: perm (blocks 0..NBLK-1) || bucketB scatter (blocks NBLK..) ----
// The two halves are mutually independent (both only feed the prop passes).
__global__ void perm_bucketB_k(const int* __restrict__ deg, const int* __restrict__ bbase,
                               const int* __restrict__ tot, int* __restrict__ perm,
                               const int* __restrict__ qtail, const int2* __restrict__ queue,
                               int* __restrict__ cursor, int* __restrict__ csrc, int n) {
    int t = threadIdx.x;
    if (blockIdx.x < NBLK) {
        __shared__ int h[64], bs[64];
        int i = blockIdx.x * 256 + t;
        if (t < 64) { h[t] = 0; bs[t] = tot[t]; }
        __syncthreads();
        if (t == 0) {
            int run = 0;
            for (int k = 0; k < 64; ++k) { int v = bs[k]; bs[k] = run; run += v; }
        }
        __syncthreads();
        if (i < n) {
            int d = deg[i]; if (d > 63) d = 63;
            int b = 63 - d;
            int rank = atomicAdd(&h[b], 1);
            perm[bs[b] + bbase[blockIdx.x * 64 + b] + rank] = i;
        }
    } else {
        int vb = blockIdx.x - NBLK;
        int J = (gridDim.x - NBLK) >> 3;
        int p = vb & 7;
        int j = vb >> 3;
        int nq = qtail[p]; if (nq > QCAP) nq = QCAP;
        const int2* q = queue + (size_t)p * QCAP;
        for (int i2 = j * 256 + t; i2 < nq; i2 += J * 256) {
            i32x2 e = __builtin_nontemporal_load((const i32x2*)q + i2);  // streaming
            int pos = atomicAdd(&cursor[e[1]], 1);
            csrc[pos] = e[0];
        }
    }
}

// ---------------- shared prop helpers ----------------
__device__ __forceinline__ void add8(float* acc, float4 v) {
    const __half2* hp = (const __half2*)&v;
    #pragma unroll
    for (int j = 0; j < 4; ++j) {
        float2 f = __half22float2(hp[j]);
        acc[2 * j] += f.x;
        acc[2 * j + 1] += f.y;
    }
}

__device__ __forceinline__ void unpack8(float* acc, float4 r) {
    const __half2* hp = (const __half2*)&r;
    #pragma unroll
    for (int j = 0; j < 4; ++j) {
        float2 f = __half22float2(hp[j]);
        acc[2 * j] = f.x;
        acc[2 * j + 1] = f.y;
    }
}

// 4-aligned gather: edge lists padded to multiples of 4 (pads hit the zero
// row): ONE nt int4 index load + FOUR float4 row-gathers per 4 edges.
// Index stream is zero-reuse -> non-temporal keeps L1/L2 for feature rows.
__device__ __forceinline__ void gather4(const float4* __restrict__ in8, int ci,
        const int* __restrict__ csrc, int r0, int r1, float* acc) {
    if (r0 >= r1) return;
    i32x4 s = __builtin_nontemporal_load((const i32x4*)(csrc + r0));
    int i = r0;
    for (; i + 4 < r1; i += 4) {
        float4 v0 = in8[(size_t)s[0] * 8 + ci];
        float4 v1 = in8[(size_t)s[1] * 8 + ci];
        float4 v2 = in8[(size_t)s[2] * 8 + ci];
        float4 v3 = in8[(size_t)s[3] * 8 + ci];
        s = __builtin_nontemporal_load((const i32x4*)(csrc + i + 4));
        add8(acc, v0); add8(acc, v1); add8(acc, v2); add8(acc, v3);
    }
    {   // last batch
        float4 v0 = in8[(size_t)s[0] * 8 + ci];
        float4 v1 = in8[(size_t)s[1] * 8 + ci];
        float4 v2 = in8[(size_t)s[2] * 8 + ci];
        float4 v3 = in8[(size_t)s[3] * 8 + ci];
        add8(acc, v0); add8(acc, v1); add8(acc, v2); add8(acc, v3);
    }
}

// ---------------- C=64 prop: 8-lane group per NODE (degree-sorted) ------------
template <bool COMBINE, bool LEAKY, bool BIAS>
__global__ void __launch_bounds__(256) prop64_k(
        const int* __restrict__ perm,
        const int* __restrict__ rowptr, const int* __restrict__ csrc,
        const float* __restrict__ dinv,
        const __half* __restrict__ in, const __half* __restrict__ h0,
        const float* __restrict__ bias,
        __half* __restrict__ out, int N) {
    int g = blockIdx.x * (blockDim.x >> 3) + (threadIdx.x >> 3);
    int ci = threadIdx.x & 7;  // 8 lanes x 8ch = 64 channels
    if (g >= N) return;
    int node = perm[g];
    const float4* in8 = (const float4*)in;
    float acc[8];
    unpack8(acc, in8[(size_t)node * 8 + ci]);  // self-loop term G[node]
    int r0 = rowptr[node], r1 = rowptr[node + 1];
    gather4(in8, ci, csrc, r0, r1, acc);
    float di = dinv[node];
    float sc = di * di;
    float v[8];
    #pragma unroll
    for (int j = 0; j < 8; ++j) v[j] = sc * acc[j];
    if (BIAS) {
        float4 b0v = ((const float4*)bias)[2 * ci];
        float4 b1v = ((const float4*)bias)[2 * ci + 1];
        v[0] += di * b0v.x; v[1] += di * b0v.y; v[2] += di * b0v.z; v[3] += di * b0v.w;
        v[4] += di * b1v.x; v[5] += di * b1v.y; v[6] += di * b1v.z; v[7] += di * b1v.w;
    }
    if (COMBINE) {
        float h[8];
        unpack8(h, ((const float4*)h0)[(size_t)node * 8 + ci]);
        #pragma unroll
        for (int j = 0; j < 8; ++j) v[j] = (1.0f - ALPHA) * v[j] + ALPHA * h[j];
    }
    if (LEAKY) {
        #pragma unroll
        for (int j = 0; j < 8; ++j) v[j] = v[j] > 0.0f ? v[j] : NEG_SLOPE * v[j];
    }
    float4 o;
    __half2* op = (__half2*)&o;
    #pragma unroll
    for (int j = 0; j < 4; ++j)
        op[j] = __float22half2_rn(make_float2(v[2 * j], v[2 * j + 1]));
    ((float4*)out)[(size_t)node * 8 + ci] = o;
}

// ---------------- C=40 prop, padded 128 B rows ----------------
__global__ void __launch_bounds__(256) prop40_k(
        const int* __restrict__ perm,
        const int* __restrict__ rowptr, const int* __restrict__ csrc,
        const float* __restrict__ dinv,
        const __half* __restrict__ in, __half* __restrict__ out, int N) {
    int g = blockIdx.x * (blockDim.x >> 3) + (threadIdx.x >> 3);
    int ci = threadIdx.x & 7;
    if (g >= N) return;
    int node = perm[g];
    bool act = ci < 5;  // 5 lanes x 8ch = 40 channels
    int cc = act ? ci : 0;
    const float4* in4 = (const float4*)in;
    float acc[8];
    unpack8(acc, in4[(size_t)node * 8 + cc]);
    int r0 = rowptr[node], r1 = rowptr[node + 1];
    gather4(in4, cc, csrc, r0, r1, acc);
    if (act) {
        float di = dinv[node];
        float sc = di * di;
        float4 o;
        __half2* op = (__half2*)&o;
        #pragma unroll
        for (int j = 0; j < 4; ++j)
            op[j] = __float22half2_rn(make_float2(sc * acc[2 * j], sc * acc[2 * j + 1]));
        ((float4*)out)[(size_t)node * 8 + ci] = o;
    }
}

// ---------------- final C=40 prop + b4 + log_softmax, fp32 out ----------------
__global__ void __launch_bounds__(256) prop40_softmax_k(
        const int* __restrict__ perm,
        const int* __restrict__ rowptr, const int* __restrict__ csrc,
        const float* __restrict__ dinv,
        const __half* __restrict__ in, const float* __restrict__ bias,
        float* __restrict__ out, int N) {
    int g = blockIdx.x * (blockDim.x >> 3) + (threadIdx.x >> 3);
    int ci = threadIdx.x & 7;
    if (g >= N) return;
    int node = perm[g];
    bool act = ci < 5;
    int cc = act ? ci : 0;
    const float4* in4 = (const float4*)in;
    float acc[8];
    unpack8(acc, in4[(size_t)node * 8 + cc]);
    int r0 = rowptr[node], r1 = rowptr[node + 1];
    gather4(in4, cc, csrc, r0, r1, acc);
    float di = dinv[node];
    float v[8];
    if (act) {
        float4 b0v = ((const float4*)bias)[2 * ci];
        float4 b1v = ((const float4*)bias)[2 * ci + 1];
        v[0] = di * acc[0] + b0v.x; v[1] = di * acc[1] + b0v.y;
        v[2] = di * acc[2] + b0v.z; v[3] = di * acc[3] + b0v.w;
        v[4] = di * acc[4] + b1v.x; v[5] = di * acc[5] + b1v.y;
        v[6] = di * acc[6] + b1v.z; v[7] = di * acc[7] + b1v.w;
    } else {
        #pragma unroll
        for (int j = 0; j < 8; ++j) v[j] = -INFINITY;
    }
    float m = v[0];
    #pragma unroll
    for (int j = 1; j < 8; ++j) m = fmaxf(m, v[j]);
    #pragma unroll
    for (int off = 4; off >= 1; off >>= 1) m = fmaxf(m, __shfl_xor(m, off));
    float e = 0.0f;
    if (act) {
        #pragma unroll
        for (int j = 0; j < 8; ++j) e += expf(v[j] - m);
    }
    #pragma unroll
    for (int off = 4; off >= 1; off >>= 1) e += __shfl_xor(e, off);
    float ls = m + logf(e);
    if (act) {
        float4 o0 = make_float4(v[0] - ls, v[1] - ls, v[2] - ls, v[3] - ls);
        float4 o1 = make_float4(v[4] - ls, v[5] - ls, v[6] - ls, v[7] - ls);
        ((float4*)out)[(size_t)node * 10 + 2 * ci] = o0;
        ((float4*)out)[(size_t)node * 10 + 2 * ci + 1] = o1;
    }
}

// ---------------- MFMA dense linear ----------------
template <int O, int K, int OP, bool FP32IN, bool SCALE>
__global__ void __launch_bounds__(256) mfma_lin_k(const void* __restrict__ in_,
                                                  const float* __restrict__ W,
                                                  const float* __restrict__ dinv,
                                                  __half* __restrict__ out, int Mtiles) {
    constexpr int P2 = 52;
    __shared__ __half2 wsh[O * P2];
    for (int idx = threadIdx.x; idx < O * (K / 2); idx += 256) {
        int o = idx / (K / 2), kk = idx - o * (K / 2);
        float2 w2 = ((const float2*)W)[o * (K / 2) + kk];
        wsh[o * P2 + kk] = __floats2half2_rn(w2.x, w2.y);
    }
    __syncthreads();
    int wave = (blockIdx.x * 256 + threadIdx.x) >> 6;
    if (wave >= Mtiles) return;
    int lane = threadIdx.x & 63;
    int lm = lane & 15, q = lane >> 4;
    long long m0 = (long long)wave * 16;
    constexpr int NT = (O + 15) / 16;
    f32x4 acc[NT];
    #pragma unroll
    for (int j = 0; j < NT; ++j) acc[j] = (f32x4){0.f, 0.f, 0.f, 0.f};
    const __half* wsp = (const __half*)wsh;
    #pragma unroll
    for (int k0 = 0; k0 < K; k0 += 32) {
        f16x8 a;
        if (FP32IN) {
            const float* xr = (const float*)in_ + (m0 + lm) * K + k0 + q * 8;
            float4 x0 = ((const float4*)xr)[0];
            float4 x1 = ((const float4*)xr)[1];
            a = (f16x8){(_Float16)x0.x, (_Float16)x0.y, (_Float16)x0.z, (_Float16)x0.w,
                        (_Float16)x1.x, (_Float16)x1.y, (_Float16)x1.z, (_Float16)x1.w};
        } else {
            const __half* xr = (const __half*)in_ + (m0 + lm) * K + k0 + q * 8;
            a = *(const f16x8*)xr;
        }
        #pragma unroll
        for (int j = 0; j < NT; ++j) {
            f16x8 b = *(const f16x8*)(wsp + (16 * j + lm) * (2 * P2) + k0 + q * 8);
            acc[j] = __builtin_amdgcn_mfma_f32_16x16x32_f16(a, b, acc[j], 0, 0, 0);
        }
    }
    #pragma unroll
    for (int r = 0; r < 4; ++r) {
        long long m = m0 + q * 4 + r;
        float sc = SCALE ? dinv[m] : 1.0f;
        #pragma unroll
        for (int j = 0; j < NT; ++j) {
            int col = 16 * j + lm;
            if (col < O) out[m * OP + col] = __float2half(acc[j][r] * sc);
        }
    }
}

// ---------------- launcher ----------------
static inline int cdiv(long long a, long long b) { return (int)((a + b - 1) / b); }
static inline size_t align256(size_t x) { return (x + 255) & ~(size_t)255; }

extern "C" void kernel_launch(void* const* d_in, const int* in_sizes, int n_in,
                              void* d_out, int out_size, void* d_ws, size_t ws_size,
                              hipStream_t stream) {
    const float* x  = (const float*)d_in[0];
    const void*  ei = d_in[1];
    const float* W0 = (const float*)d_in[2];
    const float* b0 = (const float*)d_in[3];
    const float* W4 = (const float*)d_in[4];
    const float* b4 = (const float*)d_in[5];
    float* out = (float*)d_out;

    const int N = N_NODES, E = N_EDGES;
    const int EP = E + 4 * N;     // padded csrc capacity
    char* ws = (char*)d_ws;
    int*    flag   = (int*)ws;     ws += 256;   // [0]=is64, [1]=scan ticket
    int*    deg    = (int*)ws;     ws += align256((size_t)N * 4);
    int*    rowptr = (int*)ws;     ws += align256((size_t)(N + 1) * 4);
    int*    cursor = (int*)ws;     ws += align256((size_t)N * 4);
    int*    part   = (int*)ws;     ws += align256(256 * 4);
    int*    bcnt   = (int*)ws;     ws += align256((size_t)NBLK * 64 * 4);
    int*    bbase  = (int*)ws;     ws += align256((size_t)NBLK * 64 * 4);
    int*    tot    = (int*)ws;     ws += align256(64 * 4);
    int*    qtail  = (int*)ws;     ws += align256(8 * 4);
    int*    perm   = (int*)ws;     ws += align256((size_t)N * 4);
    float*  dinv   = (float*)ws;   ws += align256((size_t)N * 4);
    int*    csrc   = (int*)ws;     ws += align256((size_t)EP * 4);
    int2*   queue  = (int2*)ws;    ws += align256((size_t)8 * QCAP * 8);
    __half* bufA   = (__half*)ws;  ws += align256((size_t)(N + 1) * HID_C * 2);
    __half* bufB   = (__half*)ws;  ws += align256((size_t)(N + 1) * HID_C * 2);
    __half* bufC   = (__half*)ws;  ws += align256((size_t)(N + 1) * HID_C * 2);

    const int T = 256;
    const int MT = N / 16;             // 3125 MFMA tiles
    const int LB = cdiv(MT, 4);        // mfma_lin blocks (4 waves each)
    const int P64B = cdiv(N, T / 8);   // prop blocks (32 groups each)

    // ---- CSR build (padded-to-4 rows; pads -> zero row N) + degree sort ----
    zero_detect_k<<<cdiv(N, T), T, 0, stream>>>(deg, N, qtail, (const unsigned int*)ei, flag,
                                                bufA, bufB, bufC);
    bucketA_k<<<cdiv(E, 1024), T, 0, stream>>>(ei, flag, deg, qtail, queue, E);
    scan_p12_k<<<NBLK, 256, 0, stream>>>(deg, part, rowptr, flag + 1, N);
    scan_p3_k<<<NBLK, 256, 0, stream>>>(deg, part, rowptr, cursor, dinv, bcnt, csrc, N);
    bscanA_k<<<64, 256, 0, stream>>>(bcnt, bbase, tot, NBLK);
    perm_bucketB_k<<<NBLK + 512, T, 0, stream>>>(deg, bbase, tot, perm,
                                                 qtail, queue, cursor, csrc, N);

    // ---- conv0 (SGConv, K=2): linear folded first; output G-space ----
    mfma_lin_k<HID_C, IN_C, HID_C, true, true><<<LB, 256, 0, stream>>>(x, W0, dinv, bufA, MT);
    prop64_k<false, false, false><<<P64B, T, 0, stream>>>(
        perm, rowptr, csrc, dinv, bufA, nullptr, nullptr, bufB, N);
    prop64_k<false, false, true><<<P64B, T, 0, stream>>>(
        perm, rowptr, csrc, dinv, bufB, nullptr, b0, bufC, N);  // + dinv*b0 -> Gh0

    // ---- conv1..conv3: leaky(APPNP(h)) entirely in G-space, Gh0 = bufC ----
    for (int r = 0; r < 3; ++r) {
        prop64_k<true, false, false><<<P64B, T, 0, stream>>>(
            perm, rowptr, csrc, dinv, bufC, bufC, nullptr, bufB, N);
        // in-place bufC write safe: Gh0[node] read only by the group writing it
        prop64_k<true, true, false><<<P64B, T, 0, stream>>>(
            perm, rowptr, csrc, dinv, bufB, bufC, nullptr, bufC, N);
    }

    // ---- conv4 (SGConv, K=2): G-space lin, then 2 hops at 40ch ----
    mfma_lin_k<OUT_C, HID_C, HID_C, false, false><<<LB, 256, 0, stream>>>(
        bufC, W4, dinv, bufA, MT);
    prop40_k<<<P64B, T, 0, stream>>>(perm, rowptr, csrc, dinv, bufA, bufB, N);
    prop40_softmax_k<<<P64B, T, 0, stream>>>(perm, rowptr, csrc, dinv, bufB, b4, out, N);
}

// Round 7
// 314.511 us; speedup vs baseline: 1.1232x; 1.1232x over previous
//
#include <hip/hip_runtime.h>
#include <hip/hip_fp16.h>
#include <math.h>

#define N_NODES 50000
#define N_EDGES 800000
#define IN_C 96
#define HID_C 64
#define OUT_C 40
#define ALPHA 0.2f
#define NEG_SLOPE 0.01f
#define QCAP 131072  // per-partition queue capacity; mean 100k, ~100 sigma margin

typedef _Float16 f16x8 __attribute__((ext_vector_type(8)));
typedef float f32x4 __attribute__((ext_vector_type(4)));

__device__ __forceinline__ int edge_at(const void* ei, int is64, long long pos) {
    return is64 ? (int)((const long long*)ei)[pos] : ((const int*)ei)[pos];
}

// ---- zero deg + qtail + zero-row init + edge dtype detect (fused) ----
// Row N_NODES of each feature buffer is the shared ZERO ROW targeted by the
// alignment-pad entries in csrc; it is never written by any other kernel.
__global__ void zero_detect_k(int* deg, int n, int* qtail, const unsigned int* ei, int* flag,
                              __half* bufA, __half* bufB, __half* bufC) {
    int i = blockIdx.x * blockDim.x + threadIdx.x;
    if (i < n) deg[i] = 0;
    if (i < 8) qtail[i] = 0;
    if (i >= 8 && i < 32) {  // 24 threads: 3 bufs x 8 float4 = zero row N
        int j = i - 8;
        __half* b = (j < 8) ? bufA : (j < 16) ? bufB : bufC;
        ((float4*)b)[(size_t)N_NODES * 8 + (j & 7)] = make_float4(0.f, 0.f, 0.f, 0.f);
    }
    if (i == 0) {
        int is64 = 1;
        for (int j = 1; j < 16; j += 2)
            if (ei[j] != 0u) is64 = 0;
        *flag = is64;
    }
}

// ---- phase A: one pass over edges; block-level partition reservation ----
__global__ void bucketA_k(const void* ei, const int* flag, int* __restrict__ deg,
                          int* __restrict__ qtail, int2* __restrict__ queue, int E) {
    __shared__ int cnt[8], qb[8];
    int f = *flag;
    int e0 = blockIdx.x * 1024;
    if (threadIdx.x < 8) cnt[threadIdx.x] = 0;
    __syncthreads();
    int s[4], d[4], p[4], r[4];
    #pragma unroll
    for (int k = 0; k < 4; ++k) {
        int e = e0 + threadIdx.x + k * 256;
        if (e < E) {
            d[k] = edge_at(ei, f, (long long)E + e);
            s[k] = edge_at(ei, f, e);
            atomicAdd(&deg[d[k]], 1);
            p[k] = d[k] / (N_NODES / 8);
            if (p[k] > 7) p[k] = 7;
            r[k] = atomicAdd(&cnt[p[k]], 1);
        } else p[k] = -1;
    }
    __syncthreads();
    if (threadIdx.x < 8) qb[threadIdx.x] = atomicAdd(&qtail[threadIdx.x], cnt[threadIdx.x]);
    __syncthreads();
    #pragma unroll
    for (int k = 0; k < 4; ++k) {
        if (p[k] >= 0) {
            int pos = qb[p[k]] + r[k];
            if (pos < QCAP) queue[(size_t)p[k] * QCAP + pos] = make_int2(s[k], d[k]);
        }
    }
}

// ---- phase B: per-partition streaming scatter into csrc ----
__global__ void bucketB_k(const int* __restrict__ qtail, const int2* __restrict__ queue,
                          int* __restrict__ cursor, int* __restrict__ csrc) {
    int p = blockIdx.x & 7;
    int j = blockIdx.x >> 3;
    int J = gridDim.x >> 3;
    int n = qtail[p]; if (n > QCAP) n = QCAP;
    const int2* q = queue + (size_t)p * QCAP;
    for (int i = j * blockDim.x + threadIdx.x; i < n; i += J * blockDim.x) {
        int2 e = q[i];
        int pos = atomicAdd(&cursor[e.y], 1);
        csrc[pos] = e.x;
    }
}

// ---- parallel 3-phase exclusive scan over PADDED deg ((d+3)&~3) ----
__global__ void scan_p1_k(const int* __restrict__ deg, int* __restrict__ part, int n) {
    __shared__ int sm[256];
    int t = threadIdx.x, i = blockIdx.x * 256 + t;
    int v = (i < n) ? ((deg[i] + 3) & ~3) : 0;
    sm[t] = v;
    __syncthreads();
    for (int off = 1; off < 256; off <<= 1) {
        int u = (t >= off) ? sm[t - off] : 0;
        __syncthreads();
        sm[t] += u;
        __syncthreads();
    }
    if (t == 255) part[blockIdx.x] = sm[255];
}

__global__ void scan_p2_k(int* part, int nb, int* rowptr, int n) {
    __shared__ int sm[256];
    int t = threadIdx.x;
    int v = (t < nb) ? part[t] : 0;
    sm[t] = v;
    __syncthreads();
    for (int off = 1; off < 256; off <<= 1) {
        int u = (t >= off) ? sm[t - off] : 0;
        __syncthreads();
        sm[t] += u;
        __syncthreads();
    }
    if (t < nb) part[t] = sm[t] - v;  // exclusive
    if (t == 255) rowptr[n] = sm[255];
}

// scan_p3 + bucket histogram + pad-slot fill (pads -> zero-row index N)
__global__ void scan_p3_k(const int* __restrict__ deg, const int* __restrict__ part,
                          int* __restrict__ rowptr, int* __restrict__ cursor,
                          float* __restrict__ dinv, int* __restrict__ bcnt,
                          int* __restrict__ csrc, int n) {
    __shared__ int sm[256];
    __shared__ int h[64];
    int t = threadIdx.x, i = blockIdx.x * 256 + t;
    if (t < 64) h[t] = 0;
    int d = (i < n) ? deg[i] : 0;
    int v = (d + 3) & ~3;
    sm[t] = v;
    __syncthreads();
    for (int off = 1; off < 256; off <<= 1) {
        int u = (t >= off) ? sm[t - off] : 0;
        __syncthreads();
        sm[t] += u;
        __syncthreads();
    }
    if (i < n) {
        int excl = sm[t] - v + part[blockIdx.x];
        rowptr[i] = excl;
        cursor[i] = excl;
        dinv[i] = rsqrtf((float)d + 1.0f);  // +1 self loop
        for (int k = d; k < v; ++k) csrc[excl + k] = N_NODES;  // pad -> zero row
        int dd = d; if (dd > 63) dd = 63;
        atomicAdd(&h[63 - dd], 1);          // bucket = 63-deg (descending)
    }
    __syncthreads();
    if (t < 64) bcnt[blockIdx.x * 64 + t] = h[t];
}

__global__ void bscanA_k(const int* __restrict__ bcnt, int* __restrict__ bbase,
                         int* __restrict__ tot, int nb) {
    __shared__ int sm[256];
    int b = blockIdx.x;
    int t = threadIdx.x;
    int v = (t < nb) ? bcnt[t * 64 + b] : 0;
    sm[t] = v;
    __syncthreads();
    for (int off = 1; off < 256; off <<= 1) {
        int u = (t >= off) ? sm[t - off] : 0;
        __syncthreads();
        sm[t] += u;
        __syncthreads();
    }
    if (t < nb) bbase[t * 64 + b] = sm[t] - v;
    if (t == 255) tot[b] = sm[255];
}

__global__ void perm_k(const int* __restrict__ deg, const int* __restrict__ bbase,
                       const int* __restrict__ tot, int* __restrict__ perm, int n) {
    __shared__ int h[64], bs[64];
    int t = threadIdx.x, i = blockIdx.x * 256 + t;
    if (t < 64) { h[t] = 0; bs[t] = tot[t]; }
    __syncthreads();
    if (t == 0) {
        int run = 0;
        for (int k = 0; k < 64; ++k) { int v = bs[k]; bs[k] = run; run += v; }
    }
    __syncthreads();
    if (i < n) {
        int d = deg[i]; if (d > 63) d = 63;
        int b = 63 - d;
        int rank = atomicAdd(&h[b], 1);
        perm[bs[b] + bbase[blockIdx.x * 64 + b] + rank] = i;
    }
}

// ---------------- shared prop helpers ----------------
__device__ __forceinline__ void add8(float* acc, float4 v) {
    const __half2* hp = (const __half2*)&v;
    #pragma unroll
    for (int j = 0; j < 4; ++j) {
        float2 f = __half22float2(hp[j]);
        acc[2 * j] += f.x;
        acc[2 * j + 1] += f.y;
    }
}

__device__ __forceinline__ void unpack8(float* acc, float4 r) {
    const __half2* hp = (const __half2*)&r;
    #pragma unroll
    for (int j = 0; j < 4; ++j) {
        float2 f = __half22float2(hp[j]);
        acc[2 * j] = f.x;
        acc[2 * j + 1] = f.y;
    }
}

// 4-aligned gather: edge lists padded to multiples of 4 (pads hit the zero
// row), so the steady state is exactly ONE int4 index load + FOUR float4
// row-gathers per 4 edges — 1.25 VMEM instrs/edge vs 2.0 before. No tails.
// NOTE (R6 lesson): csrc must stay normally-cached — it is re-read by all
// 10 passes and lives in L2/L3; nontemporal loads here cost ~35 µs total.
__device__ __forceinline__ void gather4(const float4* __restrict__ in8, int ci,
        const int* __restrict__ csrc, int r0, int r1, float* acc) {
    if (r0 >= r1) return;
    int4 s = *(const int4*)(csrc + r0);
    int i = r0;
    for (; i + 4 < r1; i += 4) {
        float4 v0 = in8[(size_t)s.x * 8 + ci];
        float4 v1 = in8[(size_t)s.y * 8 + ci];
        float4 v2 = in8[(size_t)s.z * 8 + ci];
        float4 v3 = in8[(size_t)s.w * 8 + ci];
        s = *(const int4*)(csrc + i + 4);
        add8(acc, v0); add8(acc, v1); add8(acc, v2); add8(acc, v3);
    }
    {   // last batch
        float4 v0 = in8[(size_t)s.x * 8 + ci];
        float4 v1 = in8[(size_t)s.y * 8 + ci];
        float4 v2 = in8[(size_t)s.z * 8 + ci];
        float4 v3 = in8[(size_t)s.w * 8 + ci];
        add8(acc, v0); add8(acc, v1); add8(acc, v2); add8(acc, v3);
    }
}

// ---------------- C=64 prop: 8-lane group per NODE (degree-sorted) ------------
template <bool COMBINE, bool LEAKY, bool BIAS>
__global__ void __launch_bounds__(256) prop64_k(
        const int* __restrict__ perm,
        const int* __restrict__ rowptr, const int* __restrict__ csrc,
        const float* __restrict__ dinv,
        const __half* __restrict__ in, const __half* __restrict__ h0,
        const float* __restrict__ bias,
        __half* __restrict__ out, int N) {
    int g = blockIdx.x * (blockDim.x >> 3) + (threadIdx.x >> 3);
    int ci = threadIdx.x & 7;  // 8 lanes x 8ch = 64 channels
    if (g >= N) return;
    int node = perm[g];
    const float4* in8 = (const float4*)in;
    float acc[8];
    unpack8(acc, in8[(size_t)node * 8 + ci]);  // self-loop term G[node]
    int r0 = rowptr[node], r1 = rowptr[node + 1];
    gather4(in8, ci, csrc, r0, r1, acc);
    float di = dinv[node];
    float sc = di * di;
    float v[8];
    #pragma unroll
    for (int j = 0; j < 8; ++j) v[j] = sc * acc[j];
    if (BIAS) {
        float4 b0v = ((const float4*)bias)[2 * ci];
        float4 b1v = ((const float4*)bias)[2 * ci + 1];
        v[0] += di * b0v.x; v[1] += di * b0v.y; v[2] += di * b0v.z; v[3] += di * b0v.w;
        v[4] += di * b1v.x; v[5] += di * b1v.y; v[6] += di * b1v.z; v[7] += di * b1v.w;
    }
    if (COMBINE) {
        float h[8];
        unpack8(h, ((const float4*)h0)[(size_t)node * 8 + ci]);
        #pragma unroll
        for (int j = 0; j < 8; ++j) v[j] = (1.0f - ALPHA) * v[j] + ALPHA * h[j];
    }
    if (LEAKY) {
        #pragma unroll
        for (int j = 0; j < 8; ++j) v[j] = v[j] > 0.0f ? v[j] : NEG_SLOPE * v[j];
    }
    float4 o;
    __half2* op = (__half2*)&o;
    #pragma unroll
    for (int j = 0; j < 4; ++j)
        op[j] = __float22half2_rn(make_float2(v[2 * j], v[2 * j + 1]));
    ((float4*)out)[(size_t)node * 8 + ci] = o;
}

// ---------------- C=40 prop, padded 128 B rows ----------------
__global__ void __launch_bounds__(256) prop40_k(
        const int* __restrict__ perm,
        const int* __restrict__ rowptr, const int* __restrict__ csrc,
        const float* __restrict__ dinv,
        const __half* __restrict__ in, __half* __restrict__ out, int N) {
    int g = blockIdx.x * (blockDim.x >> 3) + (threadIdx.x >> 3);
    int ci = threadIdx.x & 7;
    if (g >= N) return;
    int node = perm[g];
    bool act = ci < 5;  // 5 lanes x 8ch = 40 channels
    int cc = act ? ci : 0;
    const float4* in4 = (const float4*)in;
    float acc[8];
    unpack8(acc, in4[(size_t)node * 8 + cc]);
    int r0 = rowptr[node], r1 = rowptr[node + 1];
    gather4(in4, cc, csrc, r0, r1, acc);
    if (act) {
        float di = dinv[node];
        float sc = di * di;
        float4 o;
        __half2* op = (__half2*)&o;
        #pragma unroll
        for (int j = 0; j < 4; ++j)
            op[j] = __float22half2_rn(make_float2(sc * acc[2 * j], sc * acc[2 * j + 1]));
        ((float4*)out)[(size_t)node * 8 + ci] = o;
    }
}

// ---------------- final C=40 prop + b4 + log_softmax, fp32 out ----------------
__global__ void __launch_bounds__(256) prop40_softmax_k(
        const int* __restrict__ perm,
        const int* __restrict__ rowptr, const int* __restrict__ csrc,
        const float* __restrict__ dinv,
        const __half* __restrict__ in, const float* __restrict__ bias,
        float* __restrict__ out, int N) {
    int g = blockIdx.x * (blockDim.x >> 3) + (threadIdx.x >> 3);
    int ci = threadIdx.x & 7;
    if (g >= N) return;
    int node = perm[g];
    bool act = ci < 5;
    int cc = act ? ci : 0;
    const float4* in4 = (const float4*)in;
    float acc[8];
    unpack8(acc, in4[(size_t)node * 8 + cc]);
    int r0 = rowptr[node], r1 = rowptr[node + 1];
    gather4(in4, cc, csrc, r0, r1, acc);
    float di = dinv[node];
    float v[8];
    if (act) {
        float4 b0v = ((const float4*)bias)[2 * ci];
        float4 b1v = ((const float4*)bias)[2 * ci + 1];
        v[0] = di * acc[0] + b0v.x; v[1] = di * acc[1] + b0v.y;
        v[2] = di * acc[2] + b0v.z; v[3] = di * acc[3] + b0v.w;
        v[4] = di * acc[4] + b1v.x; v[5] = di * acc[5] + b1v.y;
        v[6] = di * acc[6] + b1v.z; v[7] = di * acc[7] + b1v.w;
    } else {
        #pragma unroll
        for (int j = 0; j < 8; ++j) v[j] = -INFINITY;
    }
    float m = v[0];
    #pragma unroll
    for (int j = 1; j < 8; ++j) m = fmaxf(m, v[j]);
    #pragma unroll
    for (int off = 4; off >= 1; off >>= 1) m = fmaxf(m, __shfl_xor(m, off));
    float e = 0.0f;
    if (act) {
        #pragma unroll
        for (int j = 0; j < 8; ++j) e += expf(v[j] - m);
    }
    #pragma unroll
    for (int off = 4; off >= 1; off >>= 1) e += __shfl_xor(e, off);
    float ls = m + logf(e);
    if (act) {
        float4 o0 = make_float4(v[0] - ls, v[1] - ls, v[2] - ls, v[3] - ls);
        float4 o1 = make_float4(v[4] - ls, v[5] - ls, v[6] - ls, v[7] - ls);
        ((float4*)out)[(size_t)node * 10 + 2 * ci] = o0;
        ((float4*)out)[(size_t)node * 10 + 2 * ci + 1] = o1;
    }
}

// ---------------- MFMA dense linear ----------------
template <int O, int K, int OP, bool FP32IN, bool SCALE>
__global__ void __launch_bounds__(256) mfma_lin_k(const void* __restrict__ in_,
                                                  const float* __restrict__ W,
                                                  const float* __restrict__ dinv,
                                                  __half* __restrict__ out, int Mtiles) {
    constexpr int P2 = 52;
    __shared__ __half2 wsh[O * P2];
    for (int idx = threadIdx.x; idx < O * (K / 2); idx += 256) {
        int o = idx / (K / 2), kk = idx - o * (K / 2);
        float2 w2 = ((const float2*)W)[o * (K / 2) + kk];
        wsh[o * P2 + kk] = __floats2half2_rn(w2.x, w2.y);
    }
    __syncthreads();
    int wave = (blockIdx.x * 256 + threadIdx.x) >> 6;
    if (wave >= Mtiles) return;
    int lane = threadIdx.x & 63;
    int lm = lane & 15, q = lane >> 4;
    long long m0 = (long long)wave * 16;
    constexpr int NT = (O + 15) / 16;
    f32x4 acc[NT];
    #pragma unroll
    for (int j = 0; j < NT; ++j) acc[j] = (f32x4){0.f, 0.f, 0.f, 0.f};
    const __half* wsp = (const __half*)wsh;
    #pragma unroll
    for (int k0 = 0; k0 < K; k0 += 32) {
        f16x8 a;
        if (FP32IN) {
            const float* xr = (const float*)in_ + (m0 + lm) * K + k0 + q * 8;
            float4 x0 = ((const float4*)xr)[0];
            float4 x1 = ((const float4*)xr)[1];
            a = (f16x8){(_Float16)x0.x, (_Float16)x0.y, (_Float16)x0.z, (_Float16)x0.w,
                        (_Float16)x1.x, (_Float16)x1.y, (_Float16)x1.z, (_Float16)x1.w};
        } else {
            const __half* xr = (const __half*)in_ + (m0 + lm) * K + k0 + q * 8;
            a = *(const f16x8*)xr;
        }
        #pragma unroll
        for (int j = 0; j < NT; ++j) {
            f16x8 b = *(const f16x8*)(wsp + (16 * j + lm) * (2 * P2) + k0 + q * 8);
            acc[j] = __builtin_amdgcn_mfma_f32_16x16x32_f16(a, b, acc[j], 0, 0, 0);
        }
    }
    #pragma unroll
    for (int r = 0; r < 4; ++r) {
        long long m = m0 + q * 4 + r;
        float sc = SCALE ? dinv[m] : 1.0f;
        #pragma unroll
        for (int j = 0; j < NT; ++j) {
            int col = 16 * j + lm;
            if (col < O) out[m * OP + col] = __float2half(acc[j][r] * sc);
        }
    }
}

// ---------------- launcher ----------------
static inline int cdiv(long long a, long long b) { return (int)((a + b - 1) / b); }
static inline size_t align256(size_t x) { return (x + 255) & ~(size_t)255; }

extern "C" void kernel_launch(void* const* d_in, const int* in_sizes, int n_in,
                              void* d_out, int out_size, void* d_ws, size_t ws_size,
                              hipStream_t stream) {
    const float* x  = (const float*)d_in[0];
    const void*  ei = d_in[1];
    const float* W0 = (const float*)d_in[2];
    const float* b0 = (const float*)d_in[3];
    const float* W4 = (const float*)d_in[4];
    const float* b4 = (const float*)d_in[5];
    float* out = (float*)d_out;

    const int N = N_NODES, E = N_EDGES;
    const int NB = cdiv(N, 256);  // 196
    const int EP = E + 4 * N;     // padded csrc capacity
    char* ws = (char*)d_ws;
    int*    flag   = (int*)ws;     ws += 256;
    int*    deg    = (int*)ws;     ws += align256((size_t)N * 4);
    int*    rowptr = (int*)ws;     ws += align256((size_t)(N + 1) * 4);
    int*    cursor = (int*)ws;     ws += align256((size_t)N * 4);
    int*    part   = (int*)ws;     ws += align256(256 * 4);
    int*    bcnt   = (int*)ws;     ws += align256((size_t)NB * 64 * 4);
    int*    bbase  = (int*)ws;     ws += align256((size_t)NB * 64 * 4);
    int*    tot    = (int*)ws;     ws += align256(64 * 4);
    int*    qtail  = (int*)ws;     ws += align256(8 * 4);
    int*    perm   = (int*)ws;     ws += align256((size_t)N * 4);
    float*  dinv   = (float*)ws;   ws += align256((size_t)N * 4);
    int*    csrc   = (int*)ws;     ws += align256((size_t)EP * 4);
    int2*   queue  = (int2*)ws;    ws += align256((size_t)8 * QCAP * 8);
    __half* bufA   = (__half*)ws;  ws += align256((size_t)(N + 1) * HID_C * 2);
    __half* bufB   = (__half*)ws;  ws += align256((size_t)(N + 1) * HID_C * 2);
    __half* bufC   = (__half*)ws;  ws += align256((size_t)(N + 1) * HID_C * 2);

    const int T = 256;
    const int MT = N / 16;             // 3125 MFMA tiles
    const int LB = cdiv(MT, 4);        // mfma_lin blocks (4 waves each)
    const int P64B = cdiv(N, T / 8);   // prop blocks (32 groups each)

    // ---- CSR build (padded-to-4 rows; pads -> zero row N) + degree sort ----
    zero_detect_k<<<cdiv(N, T), T, 0, stream>>>(deg, N, qtail, (const unsigned int*)ei, flag,
                                                bufA, bufB, bufC);
    bucketA_k<<<cdiv(E, 1024), T, 0, stream>>>(ei, flag, deg, qtail, queue, E);
    scan_p1_k<<<NB, 256, 0, stream>>>(deg, part, N);
    scan_p2_k<<<1, 256, 0, stream>>>(part, NB, rowptr, N);
    scan_p3_k<<<NB, 256, 0, stream>>>(deg, part, rowptr, cursor, dinv, bcnt, csrc, N);
    bscanA_k<<<64, 256, 0, stream>>>(bcnt, bbase, tot, NB);
    perm_k<<<NB, 256, 0, stream>>>(deg, bbase, tot, perm, N);
    bucketB_k<<<8 * 64, T, 0, stream>>>(qtail, queue, cursor, csrc);

    // ---- conv0 (SGConv, K=2): linear folded first; output G-space ----
    mfma_lin_k<HID_C, IN_C, HID_C, true, true><<<LB, 256, 0, stream>>>(x, W0, dinv, bufA, MT);
    prop64_k<false, false, false><<<P64B, T, 0, stream>>>(
        perm, rowptr, csrc, dinv, bufA, nullptr, nullptr, bufB, N);
    prop64_k<false, false, true><<<P64B, T, 0, stream>>>(
        perm, rowptr, csrc, dinv, bufB, nullptr, b0, bufC, N);  // + dinv*b0 -> Gh0

    // ---- conv1..conv3: leaky(APPNP(h)) entirely in G-space, Gh0 = bufC ----
    for (int r = 0; r < 3; ++r) {
        prop64_k<true, false, false><<<P64B, T, 0, stream>>>(
            perm, rowptr, csrc, dinv, bufC, bufC, nullptr, bufB, N);
        // in-place bufC write safe: Gh0[node] read only by the group writing it
        prop64_k<true, true, false><<<P64B, T, 0, stream>>>(
            perm, rowptr, csrc, dinv, bufB, bufC, nullptr, bufC, N);
    }

    // ---- conv4 (SGConv, K=2): G-space lin, then 2 hops at 40ch ----
    mfma_lin_k<OUT_C, HID_C, HID_C, false, false><<<LB, 256, 0, stream>>>(
        bufC, W4, dinv, bufA, MT);
    prop40_k<<<P64B, T, 0, stream>>>(perm, rowptr, csrc, dinv, bufA, bufB, N);
    prop40_softmax_k<<<P64B, T, 0, stream>>>(perm, rowptr, csrc, dinv, bufB, b4, out, N);
}